// Round 6
// baseline (65.680 us; speedup 1.0000x reference)
//
#include <hip/hip_runtime.h>

#define B 64
#define C 2048
#define L 1024
#define WCHUNK 256            // w values per block
#define NBLK_W (L / WCHUNK)   // 4 -> grid = 64*4 = 256 blocks
#define NC 4                  // c values per thread (register blocking)
#define WSUB 64               // w values per thread
#define NBLOCKS (B * NBLK_W)  // 256 partials
#define FLAG_MAGIC 1

__global__ __launch_bounds__(1024)
void rank_fused_kernel(const float* __restrict__ ranks,
                       const int* __restrict__ labels,
                       const int* __restrict__ ids,   // int32 (jax x64-disabled)
                       float* __restrict__ partials,  // d_ws[0..255]
                       int* __restrict__ flags,       // d_ws+256 floats; poison!=1
                       float* __restrict__ out)
{
    // Mask fused into values: non-neg w -> -1e30 (relu kills it),
    // non-pos c -> +1e30 (base = 0.03 - rc = -huge, relu kills the row).
    __shared__ float s_rw[L];
    __shared__ float s_rc[L];
    __shared__ float s_partial[16];

    const int blk = blockIdx.x;
    const int b   = blk / NBLK_W;
    const int wc  = blk % NBLK_W;
    const int t   = threadIdx.x;

    {
        const int id  = ids[t];
        const float r = ranks[b * C + id];
        const int lab = labels[b * C + id];
        const bool pos = (lab == 1);
        s_rw[t] = pos ? -1e30f : r;
        s_rc[t] = pos ? r : 1e30f;
    }
    __syncthreads();

    const int i = t & 255;        // c-group: owns c = i + 256*k
    const int j = t >> 8;         // wave-uniform w-subchunk -> pure LDS broadcast

    float base[NC];
    #pragma unroll
    for (int k = 0; k < NC; ++k)
        base[k] = 0.03f - s_rc[i + 256 * k];

    float acc[NC] = {0.f, 0.f, 0.f, 0.f};
    const int w0 = wc * WCHUNK + j * WSUB;

    #pragma unroll 4
    for (int it = 0; it < WSUB / 4; ++it) {
        const float4 rw = *(const float4*)&s_rw[w0 + it * 4];   // ds_read_b128 broadcast
        #pragma unroll
        for (int k = 0; k < NC; ++k) {
            acc[k] += fmaxf(rw.x + base[k], 0.0f);
            acc[k] += fmaxf(rw.y + base[k], 0.0f);
            acc[k] += fmaxf(rw.z + base[k], 0.0f);
            acc[k] += fmaxf(rw.w + base[k], 0.0f);
        }
    }

    float v = (acc[0] + acc[1]) + (acc[2] + acc[3]);

    #pragma unroll
    for (int off = 32; off > 0; off >>= 1)
        v += __shfl_down(v, off, 64);

    const int lane = t & 63;
    const int wave = t >> 6;
    if (lane == 0) s_partial[wave] = v;
    __syncthreads();

    if (wave == 0) {
        float s = (lane < 16) ? s_partial[lane] : 0.0f;
        #pragma unroll
        for (int off = 8; off > 0; off >>= 1)
            s += __shfl_down(s, off, 64);
        if (lane == 0) {
            // Publish partial: relaxed data store, release flag store (agent scope).
            __hip_atomic_store(&partials[blk], s, __ATOMIC_RELAXED,
                               __HIP_MEMORY_SCOPE_AGENT);
            __hip_atomic_store(&flags[blk], FLAG_MAGIC, __ATOMIC_RELEASE,
                               __HIP_MEMORY_SCOPE_AGENT);
        }

        // Block 0, wave 0: consume all 256 partials. All 256 blocks (16 waves,
        // 8.2KB LDS) are co-resident on 256 CUs -> spin cannot deadlock.
        if (blk == 0) {
            float tot = 0.0f;
            #pragma unroll
            for (int k = 0; k < NBLOCKS / 64; ++k) {
                const int idx = lane + 64 * k;
                while (__hip_atomic_load(&flags[idx], __ATOMIC_ACQUIRE,
                                         __HIP_MEMORY_SCOPE_AGENT) != FLAG_MAGIC) {
                    __builtin_amdgcn_s_sleep(1);
                }
                tot += __hip_atomic_load(&partials[idx], __ATOMIC_RELAXED,
                                         __HIP_MEMORY_SCOPE_AGENT);
            }
            #pragma unroll
            for (int off = 32; off > 0; off >>= 1)
                tot += __shfl_down(tot, off, 64);
            if (lane == 0)
                out[0] = tot * (1.0f / B);
        }
    }
}

extern "C" void kernel_launch(void* const* d_in, const int* in_sizes, int n_in,
                              void* d_out, int out_size, void* d_ws, size_t ws_size,
                              hipStream_t stream) {
    const float* ranks = (const float*)d_in[0];
    const int* labels  = (const int*)d_in[1];
    const int* ids     = (const int*)d_in[2];
    float* out         = (float*)d_out;
    float* partials    = (float*)d_ws;
    int* flags         = (int*)((char*)d_ws + NBLOCKS * sizeof(float));

    rank_fused_kernel<<<NBLOCKS, 1024, 0, stream>>>(ranks, labels, ids,
                                                    partials, flags, out);
}

// Round 7
// 62.763 us; speedup vs baseline: 1.0465x; 1.0465x over previous
//
#include <hip/hip_runtime.h>

// RankingLoss: sum_{b,pos c,neg w} relu(0.03 + r[b,w] - r[b,c]) / B
// over r = ranks[:, ids], lab = labels[:, ids]; B=64, C=2048, L=1024.
//
// Final form (R5, best measured 64.46 us). The timed duration is dominated
// by harness fixed costs: 268 MB d_ws re-poison fill (~40 us @ 84% HBM peak,
// top dispatch in every profile) + per-replay restore/launch overhead
// (~20 us). Kernel compute is ~4 us (201M VALU lane-ops = 2.6 us + 1 MB
// gather). Structural changes of 10x+ (16x LDS-issue cut R4, atomic removal
// R5, dispatch fusion R6) each moved total by <=2% -- harness-floor bound.

#define B 64
#define C 2048
#define L 1024
#define WCHUNK 256            // w values per block
#define NBLK_W (L / WCHUNK)   // 4 -> grid = 64*4 = 256 blocks
#define NC 4                  // c values per thread (register blocking)
#define WSUB 64               // w values per thread
#define NBLOCKS (B * NBLK_W)  // 256 partials

__global__ __launch_bounds__(1024)
void rank_partial_kernel(const float* __restrict__ ranks,
                         const int* __restrict__ labels,
                         const int* __restrict__ ids,   // int32 (jax x64-disabled)
                         float* __restrict__ partials)
{
    // Mask fused into values: non-neg w -> -1e30 (relu kills it),
    // non-pos c -> +1e30 (base = 0.03 - rc = -huge, relu kills the row).
    __shared__ float s_rw[L];    // w-role: r if label!=1 else -1e30
    __shared__ float s_rc[L];    // c-role: r if label==1 else +1e30
    __shared__ float s_partial[16];

    const int b  = blockIdx.x / NBLK_W;
    const int wc = blockIdx.x % NBLK_W;
    const int t  = threadIdx.x;

    {
        const int id  = ids[t];
        const float r = ranks[b * C + id];
        const int lab = labels[b * C + id];
        const bool pos = (lab == 1);
        s_rw[t] = pos ? -1e30f : r;
        s_rc[t] = pos ? r : 1e30f;
    }
    __syncthreads();

    const int i = t & 255;        // c-group: owns c = i + 256*k
    const int j = t >> 8;         // wave-uniform w-subchunk -> pure LDS broadcast

    float base[NC];
    #pragma unroll
    for (int k = 0; k < NC; ++k)
        base[k] = 0.03f - s_rc[i + 256 * k];

    float acc[NC] = {0.f, 0.f, 0.f, 0.f};
    const int w0 = wc * WCHUNK + j * WSUB;

    #pragma unroll 4
    for (int it = 0; it < WSUB / 4; ++it) {
        const float4 rw = *(const float4*)&s_rw[w0 + it * 4];   // ds_read_b128 broadcast
        #pragma unroll
        for (int k = 0; k < NC; ++k) {
            acc[k] += fmaxf(rw.x + base[k], 0.0f);
            acc[k] += fmaxf(rw.y + base[k], 0.0f);
            acc[k] += fmaxf(rw.z + base[k], 0.0f);
            acc[k] += fmaxf(rw.w + base[k], 0.0f);
        }
    }

    float v = (acc[0] + acc[1]) + (acc[2] + acc[3]);

    #pragma unroll
    for (int off = 32; off > 0; off >>= 1)
        v += __shfl_down(v, off, 64);

    const int lane = t & 63;
    const int wave = t >> 6;
    if (lane == 0) s_partial[wave] = v;
    __syncthreads();

    if (wave == 0) {
        float s = (lane < 16) ? s_partial[lane] : 0.0f;
        #pragma unroll
        for (int off = 8; off > 0; off >>= 1)
            s += __shfl_down(s, off, 64);
        if (lane == 0)
            partials[blockIdx.x] = s;   // plain store, overwrites poison
    }
}

__global__ __launch_bounds__(64)
void rank_final_kernel(const float* __restrict__ partials,
                       float* __restrict__ out)
{
    const int lane = threadIdx.x;   // 64 lanes, 4 partials each
    float s = 0.0f;
    #pragma unroll
    for (int k = 0; k < NBLOCKS / 64; ++k)
        s += partials[lane + 64 * k];
    #pragma unroll
    for (int off = 32; off > 0; off >>= 1)
        s += __shfl_down(s, off, 64);
    if (lane == 0)
        out[0] = s * (1.0f / B);     // plain store, no zeroing pass needed
}

extern "C" void kernel_launch(void* const* d_in, const int* in_sizes, int n_in,
                              void* d_out, int out_size, void* d_ws, size_t ws_size,
                              hipStream_t stream) {
    const float* ranks = (const float*)d_in[0];
    const int* labels  = (const int*)d_in[1];
    const int* ids     = (const int*)d_in[2];
    float* out         = (float*)d_out;
    float* partials    = (float*)d_ws;

    rank_partial_kernel<<<NBLOCKS, 1024, 0, stream>>>(ranks, labels, ids, partials);
    rank_final_kernel<<<1, 64, 0, stream>>>(partials, out);
}